// Round 4
// baseline (388.277 us; speedup 1.0000x reference)
//
#include <hip/hip_runtime.h>
#include <hip/hip_fp16.h>
#include <type_traits>

// ---------------- histogram of dst (in-degree) ----------------

__global__ void hist_kernel(const int* __restrict__ dst, int* __restrict__ counts, int E) {
    int e = blockIdx.x * blockDim.x + threadIdx.x;
    if (e < E) atomicAdd(&counts[dst[e]], 1);
}

// ---------------- 3-phase exclusive scan over counts[N] ----------------

__global__ void scan1_kernel(const int* __restrict__ counts, int* __restrict__ offs,
                             int* __restrict__ bsums, int N) {
    __shared__ int lds[256];
    int tid = threadIdx.x;
    int base = blockIdx.x * 1024 + tid * 4;
    int c0 = (base + 0 < N) ? counts[base + 0] : 0;
    int c1 = (base + 1 < N) ? counts[base + 1] : 0;
    int c2 = (base + 2 < N) ? counts[base + 2] : 0;
    int c3 = (base + 3 < N) ? counts[base + 3] : 0;
    int tsum = c0 + c1 + c2 + c3;
    lds[tid] = tsum;
    __syncthreads();
    for (int off = 1; off < 256; off <<= 1) {
        int v = (tid >= off) ? lds[tid - off] : 0;
        __syncthreads();
        lds[tid] += v;
        __syncthreads();
    }
    int texc = lds[tid] - tsum;
    if (base + 0 < N) offs[base + 0] = texc;
    if (base + 1 < N) offs[base + 1] = texc + c0;
    if (base + 2 < N) offs[base + 2] = texc + c0 + c1;
    if (base + 3 < N) offs[base + 3] = texc + c0 + c1 + c2;
    if (tid == 255) bsums[blockIdx.x] = lds[255];
}

__global__ void scan2_kernel(int* __restrict__ bsums, int NB) {
    __shared__ int lds[256];
    int tid = threadIdx.x;
    int v = (tid < NB) ? bsums[tid] : 0;
    lds[tid] = v;
    __syncthreads();
    for (int off = 1; off < 256; off <<= 1) {
        int x = (tid >= off) ? lds[tid - off] : 0;
        __syncthreads();
        lds[tid] += x;
        __syncthreads();
    }
    if (tid < NB) bsums[tid] = lds[tid] - v;
}

__global__ void finalize_kernel(int* __restrict__ offs, int* __restrict__ cursor,
                                const int* __restrict__ bsums, const int* __restrict__ counts,
                                float* __restrict__ dinv, int N) {
    int i = blockIdx.x * blockDim.x + threadIdx.x;
    if (i < N) {
        int o = offs[i] + bsums[i >> 10];
        offs[i] = o;
        cursor[i] = o;
        dinv[i] = rsqrtf((float)counts[i] + 1.0f);  // +1 self-loop
    }
}

// ---------------- scatter edges into CSR (4B src index only) ----------------

__global__ void scatter_kernel(const int* __restrict__ src, const int* __restrict__ dst,
                               int* __restrict__ cursor, int* __restrict__ ssrc, int E) {
    int e = blockIdx.x * blockDim.x + threadIdx.x;
    if (e < E) {
        int p = atomicAdd(&cursor[dst[e]], 1);
        ssrc[p] = src[e];
    }
}

// ---------------- dense X(M x 64) @ W(64 x OUTD) -> fp16 ----------------

__device__ inline float cvt_f(float v) { return v; }
__device__ inline float cvt_f(__half v) { return __half2float(v); }

template <int OUTD, typename TIN>
__global__ void gemm_kernel(const TIN* __restrict__ X, const float* __restrict__ W,
                            __half* __restrict__ H, int M) {
    constexpr int K    = 64;
    constexpr int ROWS = 1024 / OUTD;
    __shared__ float ws[K][OUTD];
    __shared__ float xs[ROWS][K + 1];

    const int tid = threadIdx.x;
    for (int i = tid; i < K * OUTD; i += 256)
        ws[i / OUTD][i % OUTD] = W[i];

    const int rowBase = blockIdx.x * ROWS;
    if constexpr (std::is_same<TIN, float>::value) {
        // ROWS*K/4 float4 loads (256 for ROWS=16, 512 for ROWS=32)
        const float4* X4 = (const float4*)X;
        for (int i = tid; i < ROWS * (K / 4); i += 256) {
            int r = i >> 4, c4 = i & 15;
            int gr = rowBase + r;
            float4 v = (gr < M) ? X4[(size_t)gr * 16 + c4] : float4{0, 0, 0, 0};
            xs[r][c4 * 4 + 0] = v.x;
            xs[r][c4 * 4 + 1] = v.y;
            xs[r][c4 * 4 + 2] = v.z;
            xs[r][c4 * 4 + 3] = v.w;
        }
    } else {
        for (int i = tid; i < ROWS * K; i += 256) {
            int r = i >> 6, c = i & 63;
            int gr = rowBase + r;
            xs[r][c] = (gr < M) ? cvt_f(X[(size_t)gr * K + c]) : 0.0f;
        }
    }
    __syncthreads();

    const int col = tid % OUTD;
    const int r0  = tid / OUTD;
    constexpr int NT_ROWS = 256 / OUTD;
    for (int r = r0; r < ROWS; r += NT_ROWS) {
        int gr = rowBase + r;
        if (gr >= M) break;
        float acc = 0.0f;
#pragma unroll
        for (int k = 0; k < K; ++k)
            acc += xs[r][k] * ws[k][col];
        H[(size_t)gr * OUTD + col] = __float2half(acc);
    }
}

// ---------------- CSR aggregation, D=64 fp16: wave/node, 4 edges per step ----------------
// out[n][:] = relu( dinv[n]*( sum h[s]*dinv[s] + h[n]*dinv[n] ) + bias )  -> fp16

__global__ void agg64_kernel(const float2* __restrict__ hrow, const int* __restrict__ ssrc,
                             const int* __restrict__ offs, const int* __restrict__ counts,
                             const float* __restrict__ dinv, const float* __restrict__ bias,
                             float2* __restrict__ outrow, int N) {
    int wid  = threadIdx.x >> 6;
    int lane = threadIdx.x & 63;
    int node = blockIdx.x * 4 + wid;
    if (node >= N) return;
    int q = lane >> 4;       // which of 4 edges per step
    int l = lane & 15;       // float2 index -> halfs 4l..4l+3
    int beg = offs[node], cnt = counts[node];
    float a0 = 0.f, a1 = 0.f, a2 = 0.f, a3 = 0.f;
    for (int base = 0; base < cnt; base += 64) {
        int rem = cnt - base;
        if (rem > 64) rem = 64;
        int idx = 0;
        float dv = 0.0f;
        if (lane < rem) {
            idx = ssrc[beg + base + lane];
            dv  = dinv[idx];
        }
        for (int k = 0; k < rem; k += 4) {
            int e = k + q;
            int   s  = __shfl(idx, e, 64);
            float nv = __shfl(dv, e, 64);
            if (e < rem) {
                float2 raw = hrow[(size_t)s * 16 + l];
                float2 f0 = __half22float2(*(const __half2*)&raw.x);
                float2 f1 = __half22float2(*(const __half2*)&raw.y);
                a0 = fmaf(f0.x, nv, a0);
                a1 = fmaf(f0.y, nv, a1);
                a2 = fmaf(f1.x, nv, a2);
                a3 = fmaf(f1.y, nv, a3);
            }
        }
    }
    a0 += __shfl_xor(a0, 16, 64);
    a1 += __shfl_xor(a1, 16, 64);
    a2 += __shfl_xor(a2, 16, 64);
    a3 += __shfl_xor(a3, 16, 64);
    a0 += __shfl_xor(a0, 32, 64);
    a1 += __shfl_xor(a1, 32, 64);
    a2 += __shfl_xor(a2, 32, 64);
    a3 += __shfl_xor(a3, 32, 64);
    if (q == 0) {
        float dd = dinv[node];
        float2 raw = hrow[(size_t)node * 16 + l];
        float2 s0 = __half22float2(*(const __half2*)&raw.x);
        float2 s1 = __half22float2(*(const __half2*)&raw.y);
        float r0 = fmaxf(dd * (a0 + s0.x * dd) + bias[4 * l + 0], 0.0f);
        float r1 = fmaxf(dd * (a1 + s0.y * dd) + bias[4 * l + 1], 0.0f);
        float r2 = fmaxf(dd * (a2 + s1.x * dd) + bias[4 * l + 2], 0.0f);
        float r3 = fmaxf(dd * (a3 + s1.y * dd) + bias[4 * l + 3], 0.0f);
        __half2 p0 = __floats2half2_rn(r0, r1);
        __half2 p1 = __floats2half2_rn(r2, r3);
        float2 w;
        w.x = *(const float*)&p0;
        w.y = *(const float*)&p1;
        outrow[(size_t)node * 16 + l] = w;
    }
}

// ---------------- CSR aggregation, D=32 fp16: wave/node, 8 edges per step -> fp32 out ----------------

__global__ void agg32_kernel(const float2* __restrict__ hrow, const int* __restrict__ ssrc,
                             const int* __restrict__ offs, const int* __restrict__ counts,
                             const float* __restrict__ dinv, const float* __restrict__ bias,
                             float4* __restrict__ outrow, int N) {
    int wid  = threadIdx.x >> 6;
    int lane = threadIdx.x & 63;
    int node = blockIdx.x * 4 + wid;
    if (node >= N) return;
    int o = lane >> 3;       // which of 8 edges per step
    int l = lane & 7;        // float2 index -> halfs 4l..4l+3 (of 32)
    int beg = offs[node], cnt = counts[node];
    float a0 = 0.f, a1 = 0.f, a2 = 0.f, a3 = 0.f;
    for (int base = 0; base < cnt; base += 64) {
        int rem = cnt - base;
        if (rem > 64) rem = 64;
        int idx = 0;
        float dv = 0.0f;
        if (lane < rem) {
            idx = ssrc[beg + base + lane];
            dv  = dinv[idx];
        }
        for (int k = 0; k < rem; k += 8) {
            int e = k + o;
            int   s  = __shfl(idx, e, 64);
            float nv = __shfl(dv, e, 64);
            if (e < rem) {
                float2 raw = hrow[(size_t)s * 8 + l];
                float2 f0 = __half22float2(*(const __half2*)&raw.x);
                float2 f1 = __half22float2(*(const __half2*)&raw.y);
                a0 = fmaf(f0.x, nv, a0);
                a1 = fmaf(f0.y, nv, a1);
                a2 = fmaf(f1.x, nv, a2);
                a3 = fmaf(f1.y, nv, a3);
            }
        }
    }
    a0 += __shfl_xor(a0, 8, 64);
    a1 += __shfl_xor(a1, 8, 64);
    a2 += __shfl_xor(a2, 8, 64);
    a3 += __shfl_xor(a3, 8, 64);
    a0 += __shfl_xor(a0, 16, 64);
    a1 += __shfl_xor(a1, 16, 64);
    a2 += __shfl_xor(a2, 16, 64);
    a3 += __shfl_xor(a3, 16, 64);
    a0 += __shfl_xor(a0, 32, 64);
    a1 += __shfl_xor(a1, 32, 64);
    a2 += __shfl_xor(a2, 32, 64);
    a3 += __shfl_xor(a3, 32, 64);
    if (o == 0) {
        float dd = dinv[node];
        float2 raw = hrow[(size_t)node * 8 + l];
        float2 s0 = __half22float2(*(const __half2*)&raw.x);
        float2 s1 = __half22float2(*(const __half2*)&raw.y);
        float4 r;
        r.x = dd * (a0 + s0.x * dd) + bias[4 * l + 0];
        r.y = dd * (a1 + s0.y * dd) + bias[4 * l + 1];
        r.z = dd * (a2 + s1.x * dd) + bias[4 * l + 2];
        r.w = dd * (a3 + s1.y * dd) + bias[4 * l + 3];
        outrow[(size_t)node * 8 + l] = r;
    }
}

// ---------------- launch ----------------

extern "C" void kernel_launch(void* const* d_in, const int* in_sizes, int n_in,
                              void* d_out, int out_size, void* d_ws, size_t ws_size,
                              hipStream_t stream) {
    const float* x  = (const float*)d_in[0];
    const int*   ei = (const int*)d_in[1];
    const float* W1 = (const float*)d_in[2];
    const float* b1 = (const float*)d_in[3];
    const float* W2 = (const float*)d_in[4];
    const float* b2 = (const float*)d_in[5];
    float* out = (float*)d_out;

    const int N = in_sizes[0] / 64;   // 100000
    const int E = in_sizes[1] / 2;    // 1200000
    const int* src = ei;
    const int* dst = ei + E;

    const int Npad = (N + 1023) & ~1023;  // 100352

    // workspace layout (4-byte units; h offset is 8B-aligned: 4*Npad+256+E is even)
    int*   counts = (int*)d_ws;               // Npad ints
    int*   offs   = counts + Npad;
    int*   cursor = offs + Npad;
    float* dinv   = (float*)(cursor + Npad);
    int*   bsums  = (int*)(dinv + Npad);      // 256 ints
    int*   ssrc   = bsums + 256;              // E ints
    __half* h    = (__half*)(ssrc + E);       // N*64 fp16 (reused as h2: N*32)
    __half* out1 = h + (size_t)N * 64;        // N*64 fp16

    const int T  = 256;
    const int NB = (N + 1023) / 1024;         // 98

    // build CSR by dst + dinv
    hipMemsetAsync(counts, 0, (size_t)N * sizeof(int), stream);
    hist_kernel<<<(E + T - 1) / T, T, 0, stream>>>(dst, counts, E);
    scan1_kernel<<<NB, T, 0, stream>>>(counts, offs, bsums, N);
    scan2_kernel<<<1, T, 0, stream>>>(bsums, NB);
    finalize_kernel<<<(N + T - 1) / T, T, 0, stream>>>(offs, cursor, bsums, counts, dinv, N);
    scatter_kernel<<<(E + T - 1) / T, T, 0, stream>>>(src, dst, cursor, ssrc, E);

    // layer 1
    gemm_kernel<64, float><<<(N + 15) / 16, T, 0, stream>>>(x, W1, h, N);
    agg64_kernel<<<(N + 3) / 4, T, 0, stream>>>((const float2*)h, ssrc, offs, counts, dinv, b1,
                                                (float2*)out1, N);

    // layer 2 (h2 reuses h buffer)
    gemm_kernel<32, __half><<<(N + 31) / 32, T, 0, stream>>>(out1, W2, h, N);
    agg32_kernel<<<(N + 3) / 4, T, 0, stream>>>((const float2*)h, ssrc, offs, counts, dinv, b2,
                                                (float4*)out, N);
}

// Round 5
// 313.307 us; speedup vs baseline: 1.2393x; 1.2393x over previous
//
#include <hip/hip_runtime.h>
#include <hip/hip_fp16.h>
#include <type_traits>

#define NBUCK 512  // dst-range buckets; R = ceil(N/NBUCK) must be <= 256

// ---------------- bucket histogram (LDS-aggregated) ----------------

__global__ void bucket_hist_kernel(const int* __restrict__ dst, int* __restrict__ bucketCnt,
                                   int E, int R) {
    __shared__ int h[NBUCK];
    int tid = threadIdx.x;
    for (int i = tid; i < NBUCK; i += blockDim.x) h[i] = 0;
    __syncthreads();
    for (int i = blockIdx.x * blockDim.x + tid; i < E; i += gridDim.x * blockDim.x)
        atomicAdd(&h[dst[i] / R], 1);
    __syncthreads();
    for (int i = tid; i < NBUCK; i += blockDim.x)
        if (h[i]) atomicAdd(&bucketCnt[i], h[i]);
}

// ---------------- scan of 512 bucket counts (single block) ----------------

__global__ void bucket_scan_kernel(const int* __restrict__ bucketCnt, int* __restrict__ bucketBase,
                                   int* __restrict__ bucketCursor) {
    __shared__ int lds[NBUCK];
    int tid = threadIdx.x;
    int v = bucketCnt[tid];
    lds[tid] = v;
    __syncthreads();
    for (int off = 1; off < NBUCK; off <<= 1) {
        int x = (tid >= off) ? lds[tid - off] : 0;
        __syncthreads();
        lds[tid] += x;
        __syncthreads();
    }
    int excl = lds[tid] - v;
    bucketBase[tid] = excl;
    bucketCursor[tid] = excl;
    if (tid == NBUCK - 1) bucketBase[NBUCK] = lds[tid];
}

// ---------------- partition edges into bucket regions (block-chunked, write-combining-safe) ----

__global__ __launch_bounds__(1024) void partition_kernel(const int* __restrict__ src,
                                                         const int* __restrict__ dst,
                                                         int* __restrict__ bucketCursor,
                                                         unsigned long long* __restrict__ pairs,
                                                         int E, int R) {
    __shared__ int h[NBUCK];
    __shared__ int base[NBUCK];
    __shared__ int lcur[NBUCK];
    const int CH = 16384;
    int start = blockIdx.x * CH;
    int count = E - start;
    if (count > CH) count = CH;
    int tid = threadIdx.x;
    if (tid < NBUCK) h[tid] = 0;
    __syncthreads();
    for (int i = tid; i < count; i += 1024)
        atomicAdd(&h[dst[start + i] / R], 1);
    __syncthreads();
    if (tid < NBUCK) {
        base[tid] = h[tid] ? atomicAdd(&bucketCursor[tid], h[tid]) : 0;
        lcur[tid] = 0;
    }
    __syncthreads();
    for (int i = tid; i < count; i += 1024) {
        int d = dst[start + i];
        int s = src[start + i];
        int b = d / R;
        int r = atomicAdd(&lcur[b], 1);
        pairs[base[b] + r] = ((unsigned long long)(unsigned)s << 32) | (unsigned)d;
    }
}

// ---------------- per-bucket CSR build: counts/offs/dinv coalesced, ssrc L2-local ----------------

__global__ void bucket_csr_kernel(const unsigned long long* __restrict__ pairs,
                                  const int* __restrict__ bucketBase, int* __restrict__ counts,
                                  int* __restrict__ offs, float* __restrict__ dinv,
                                  int* __restrict__ ssrc, int N, int R) {
    __shared__ int h[256];
    __shared__ int loffs[256];
    __shared__ int cur[256];
    int b = blockIdx.x, tid = threadIdx.x;
    int nodeBase = b * R;
    int beg = bucketBase[b], end = bucketBase[b + 1];
    h[tid] = 0;
    __syncthreads();
    for (int i = beg + tid; i < end; i += 256) {
        int d = (int)(pairs[i] & 0xffffffffull);
        atomicAdd(&h[d - nodeBase], 1);
    }
    __syncthreads();
    int v = h[tid];
    loffs[tid] = v;
    __syncthreads();
    for (int off = 1; off < 256; off <<= 1) {
        int x = (tid >= off) ? loffs[tid - off] : 0;
        __syncthreads();
        loffs[tid] += x;
        __syncthreads();
    }
    int excl = loffs[tid] - v;
    cur[tid] = excl;
    int node = nodeBase + tid;
    if (tid < R && node < N) {
        counts[node] = v;
        offs[node] = beg + excl;
        dinv[node] = rsqrtf((float)v + 1.0f);  // +1 self-loop
    }
    __syncthreads();
    for (int i = beg + tid; i < end; i += 256) {
        unsigned long long p = pairs[i];
        int d = (int)(p & 0xffffffffull);
        int s = (int)(p >> 32);
        int r = atomicAdd(&cur[d - nodeBase], 1);
        ssrc[beg + r] = s;
    }
}

// ---------------- dense X(M x 64) @ W(64 x OUTD) -> fp16 ----------------

__device__ inline float cvt_f(float v) { return v; }
__device__ inline float cvt_f(__half v) { return __half2float(v); }

template <int OUTD, typename TIN>
__global__ void gemm_kernel(const TIN* __restrict__ X, const float* __restrict__ W,
                            __half* __restrict__ H, int M) {
    constexpr int K    = 64;
    constexpr int ROWS = 1024 / OUTD;
    __shared__ float ws[K][OUTD];
    __shared__ float xs[ROWS][K + 1];

    const int tid = threadIdx.x;
    for (int i = tid; i < K * OUTD; i += 256)
        ws[i / OUTD][i % OUTD] = W[i];

    const int rowBase = blockIdx.x * ROWS;
    if constexpr (std::is_same<TIN, float>::value) {
        const float4* X4 = (const float4*)X;
        for (int i = tid; i < ROWS * (K / 4); i += 256) {
            int r = i >> 4, c4 = i & 15;
            int gr = rowBase + r;
            float4 v = (gr < M) ? X4[(size_t)gr * 16 + c4] : float4{0, 0, 0, 0};
            xs[r][c4 * 4 + 0] = v.x;
            xs[r][c4 * 4 + 1] = v.y;
            xs[r][c4 * 4 + 2] = v.z;
            xs[r][c4 * 4 + 3] = v.w;
        }
    } else {
        for (int i = tid; i < ROWS * K; i += 256) {
            int r = i >> 6, c = i & 63;
            int gr = rowBase + r;
            xs[r][c] = (gr < M) ? cvt_f(X[(size_t)gr * K + c]) : 0.0f;
        }
    }
    __syncthreads();

    const int col = tid % OUTD;
    const int r0  = tid / OUTD;
    constexpr int NT_ROWS = 256 / OUTD;
    for (int r = r0; r < ROWS; r += NT_ROWS) {
        int gr = rowBase + r;
        if (gr >= M) break;
        float acc = 0.0f;
#pragma unroll
        for (int k = 0; k < K; ++k)
            acc += xs[r][k] * ws[k][col];
        H[(size_t)gr * OUTD + col] = __float2half(acc);
    }
}

// ---------------- CSR aggregation, D=64 fp16: wave/node, 4 edges per step ----------------

__global__ void agg64_kernel(const float2* __restrict__ hrow, const int* __restrict__ ssrc,
                             const int* __restrict__ offs, const int* __restrict__ counts,
                             const float* __restrict__ dinv, const float* __restrict__ bias,
                             float2* __restrict__ outrow, int N) {
    int wid  = threadIdx.x >> 6;
    int lane = threadIdx.x & 63;
    int node = blockIdx.x * 4 + wid;
    if (node >= N) return;
    int q = lane >> 4;
    int l = lane & 15;
    int beg = offs[node], cnt = counts[node];
    float a0 = 0.f, a1 = 0.f, a2 = 0.f, a3 = 0.f;
    for (int base = 0; base < cnt; base += 64) {
        int rem = cnt - base;
        if (rem > 64) rem = 64;
        int idx = 0;
        float dv = 0.0f;
        if (lane < rem) {
            idx = ssrc[beg + base + lane];
            dv  = dinv[idx];
        }
        for (int k = 0; k < rem; k += 4) {
            int e = k + q;
            int   s  = __shfl(idx, e, 64);
            float nv = __shfl(dv, e, 64);
            if (e < rem) {
                float2 raw = hrow[(size_t)s * 16 + l];
                float2 f0 = __half22float2(*(const __half2*)&raw.x);
                float2 f1 = __half22float2(*(const __half2*)&raw.y);
                a0 = fmaf(f0.x, nv, a0);
                a1 = fmaf(f0.y, nv, a1);
                a2 = fmaf(f1.x, nv, a2);
                a3 = fmaf(f1.y, nv, a3);
            }
        }
    }
    a0 += __shfl_xor(a0, 16, 64);
    a1 += __shfl_xor(a1, 16, 64);
    a2 += __shfl_xor(a2, 16, 64);
    a3 += __shfl_xor(a3, 16, 64);
    a0 += __shfl_xor(a0, 32, 64);
    a1 += __shfl_xor(a1, 32, 64);
    a2 += __shfl_xor(a2, 32, 64);
    a3 += __shfl_xor(a3, 32, 64);
    if (q == 0) {
        float dd = dinv[node];
        float2 raw = hrow[(size_t)node * 16 + l];
        float2 s0 = __half22float2(*(const __half2*)&raw.x);
        float2 s1 = __half22float2(*(const __half2*)&raw.y);
        float r0 = fmaxf(dd * (a0 + s0.x * dd) + bias[4 * l + 0], 0.0f);
        float r1 = fmaxf(dd * (a1 + s0.y * dd) + bias[4 * l + 1], 0.0f);
        float r2 = fmaxf(dd * (a2 + s1.x * dd) + bias[4 * l + 2], 0.0f);
        float r3 = fmaxf(dd * (a3 + s1.y * dd) + bias[4 * l + 3], 0.0f);
        __half2 p0 = __floats2half2_rn(r0, r1);
        __half2 p1 = __floats2half2_rn(r2, r3);
        float2 w;
        w.x = *(const float*)&p0;
        w.y = *(const float*)&p1;
        outrow[(size_t)node * 16 + l] = w;
    }
}

// ---------------- CSR aggregation, D=32 fp16: wave/node, 8 edges per step -> fp32 out ----------------

__global__ void agg32_kernel(const float2* __restrict__ hrow, const int* __restrict__ ssrc,
                             const int* __restrict__ offs, const int* __restrict__ counts,
                             const float* __restrict__ dinv, const float* __restrict__ bias,
                             float4* __restrict__ outrow, int N) {
    int wid  = threadIdx.x >> 6;
    int lane = threadIdx.x & 63;
    int node = blockIdx.x * 4 + wid;
    if (node >= N) return;
    int o = lane >> 3;
    int l = lane & 7;
    int beg = offs[node], cnt = counts[node];
    float a0 = 0.f, a1 = 0.f, a2 = 0.f, a3 = 0.f;
    for (int base = 0; base < cnt; base += 64) {
        int rem = cnt - base;
        if (rem > 64) rem = 64;
        int idx = 0;
        float dv = 0.0f;
        if (lane < rem) {
            idx = ssrc[beg + base + lane];
            dv  = dinv[idx];
        }
        for (int k = 0; k < rem; k += 8) {
            int e = k + o;
            int   s  = __shfl(idx, e, 64);
            float nv = __shfl(dv, e, 64);
            if (e < rem) {
                float2 raw = hrow[(size_t)s * 8 + l];
                float2 f0 = __half22float2(*(const __half2*)&raw.x);
                float2 f1 = __half22float2(*(const __half2*)&raw.y);
                a0 = fmaf(f0.x, nv, a0);
                a1 = fmaf(f0.y, nv, a1);
                a2 = fmaf(f1.x, nv, a2);
                a3 = fmaf(f1.y, nv, a3);
            }
        }
    }
    a0 += __shfl_xor(a0, 8, 64);
    a1 += __shfl_xor(a1, 8, 64);
    a2 += __shfl_xor(a2, 8, 64);
    a3 += __shfl_xor(a3, 8, 64);
    a0 += __shfl_xor(a0, 16, 64);
    a1 += __shfl_xor(a1, 16, 64);
    a2 += __shfl_xor(a2, 16, 64);
    a3 += __shfl_xor(a3, 16, 64);
    a0 += __shfl_xor(a0, 32, 64);
    a1 += __shfl_xor(a1, 32, 64);
    a2 += __shfl_xor(a2, 32, 64);
    a3 += __shfl_xor(a3, 32, 64);
    if (o == 0) {
        float dd = dinv[node];
        float2 raw = hrow[(size_t)node * 8 + l];
        float2 s0 = __half22float2(*(const __half2*)&raw.x);
        float2 s1 = __half22float2(*(const __half2*)&raw.y);
        float4 r;
        r.x = dd * (a0 + s0.x * dd) + bias[4 * l + 0];
        r.y = dd * (a1 + s0.y * dd) + bias[4 * l + 1];
        r.z = dd * (a2 + s1.x * dd) + bias[4 * l + 2];
        r.w = dd * (a3 + s1.y * dd) + bias[4 * l + 3];
        outrow[(size_t)node * 8 + l] = r;
    }
}

// ---------------- launch ----------------

extern "C" void kernel_launch(void* const* d_in, const int* in_sizes, int n_in,
                              void* d_out, int out_size, void* d_ws, size_t ws_size,
                              hipStream_t stream) {
    const float* x  = (const float*)d_in[0];
    const int*   ei = (const int*)d_in[1];
    const float* W1 = (const float*)d_in[2];
    const float* b1 = (const float*)d_in[3];
    const float* W2 = (const float*)d_in[4];
    const float* b2 = (const float*)d_in[5];
    float* out = (float*)d_out;

    const int N = in_sizes[0] / 64;   // 100000
    const int E = in_sizes[1] / 2;    // 1200000
    const int* src = ei;
    const int* dst = ei + E;

    const int Npad = (N + 1023) & ~1023;      // 100352
    const int R    = (N + NBUCK - 1) / NBUCK; // 196 (<= 256 required by bucket_csr)

    // workspace layout (pairs first so 8B alignment is trivial)
    unsigned long long* pairs = (unsigned long long*)d_ws;    // E
    int*   ssrc   = (int*)(pairs + E);                        // E
    int*   counts = ssrc + E;                                 // Npad
    int*   offs   = counts + Npad;                            // Npad
    float* dinv   = (float*)(offs + Npad);                    // Npad
    int*   bucketCnt    = (int*)(dinv + Npad);                // NBUCK
    int*   bucketBase   = bucketCnt + NBUCK;                  // NBUCK+1
    int*   bucketCursor = bucketBase + NBUCK + 1;             // NBUCK (+1 pad)
    __half* h    = (__half*)(bucketCursor + NBUCK + 1);       // N*64 fp16 (8B-aligned)
    __half* out1 = h + (size_t)N * 64;                        // N*64 fp16

    const int T = 256;

    // CSR build (bucketed, write-combining-friendly)
    hipMemsetAsync(bucketCnt, 0, NBUCK * sizeof(int), stream);
    bucket_hist_kernel<<<512, T, 0, stream>>>(dst, bucketCnt, E, R);
    bucket_scan_kernel<<<1, NBUCK, 0, stream>>>(bucketCnt, bucketBase, bucketCursor);
    partition_kernel<<<(E + 16383) / 16384, 1024, 0, stream>>>(src, dst, bucketCursor, pairs, E, R);
    bucket_csr_kernel<<<NBUCK, T, 0, stream>>>(pairs, bucketBase, counts, offs, dinv, ssrc, N, R);

    // layer 1
    gemm_kernel<64, float><<<(N + 15) / 16, T, 0, stream>>>(x, W1, h, N);
    agg64_kernel<<<(N + 3) / 4, T, 0, stream>>>((const float2*)h, ssrc, offs, counts, dinv, b1,
                                                (float2*)out1, N);

    // layer 2 (h2 reuses h buffer)
    gemm_kernel<32, __half><<<(N + 31) / 32, T, 0, stream>>>(out1, W2, h, N);
    agg32_kernel<<<(N + 3) / 4, T, 0, stream>>>((const float2*)h, ssrc, offs, counts, dinv, b2,
                                                (float4*)out, N);
}

// Round 6
// 248.734 us; speedup vs baseline: 1.5610x; 1.2596x over previous
//
#include <hip/hip_runtime.h>
#include <hip/hip_fp16.h>
#include <type_traits>

#define NBUCK 512  // dst-range buckets; R = ceil(N/NBUCK) must be <= 256

typedef _Float16 half8 __attribute__((ext_vector_type(8)));
typedef float floatx4 __attribute__((ext_vector_type(4)));

// ---------------- bucket histogram (LDS-aggregated) ----------------

__global__ void bucket_hist_kernel(const int* __restrict__ dst, int* __restrict__ bucketCnt,
                                   int E, int R) {
    __shared__ int h[NBUCK];
    int tid = threadIdx.x;
    for (int i = tid; i < NBUCK; i += blockDim.x) h[i] = 0;
    __syncthreads();
    for (int i = blockIdx.x * blockDim.x + tid; i < E; i += gridDim.x * blockDim.x)
        atomicAdd(&h[dst[i] / R], 1);
    __syncthreads();
    for (int i = tid; i < NBUCK; i += blockDim.x)
        if (h[i]) atomicAdd(&bucketCnt[i], h[i]);
}

// ---------------- scan of 512 bucket counts (single block) ----------------

__global__ void bucket_scan_kernel(const int* __restrict__ bucketCnt, int* __restrict__ bucketBase,
                                   int* __restrict__ bucketCursor) {
    __shared__ int lds[NBUCK];
    int tid = threadIdx.x;
    int v = bucketCnt[tid];
    lds[tid] = v;
    __syncthreads();
    for (int off = 1; off < NBUCK; off <<= 1) {
        int x = (tid >= off) ? lds[tid - off] : 0;
        __syncthreads();
        lds[tid] += x;
        __syncthreads();
    }
    int excl = lds[tid] - v;
    bucketBase[tid] = excl;
    bucketCursor[tid] = excl;
    if (tid == NBUCK - 1) bucketBase[NBUCK] = lds[tid];
}

// ---------------- partition edges into bucket regions (block-chunked, write-combining-safe) ----

__global__ __launch_bounds__(1024) void partition_kernel(const int* __restrict__ src,
                                                         const int* __restrict__ dst,
                                                         int* __restrict__ bucketCursor,
                                                         unsigned long long* __restrict__ pairs,
                                                         int E, int R) {
    __shared__ int h[NBUCK];
    __shared__ int base[NBUCK];
    __shared__ int lcur[NBUCK];
    const int CH = 16384;
    int start = blockIdx.x * CH;
    int count = E - start;
    if (count > CH) count = CH;
    int tid = threadIdx.x;
    if (tid < NBUCK) h[tid] = 0;
    __syncthreads();
    for (int i = tid; i < count; i += 1024)
        atomicAdd(&h[dst[start + i] / R], 1);
    __syncthreads();
    if (tid < NBUCK) {
        base[tid] = h[tid] ? atomicAdd(&bucketCursor[tid], h[tid]) : 0;
        lcur[tid] = 0;
    }
    __syncthreads();
    for (int i = tid; i < count; i += 1024) {
        int d = dst[start + i];
        int s = src[start + i];
        int b = d / R;
        int r = atomicAdd(&lcur[b], 1);
        pairs[base[b] + r] = ((unsigned long long)(unsigned)s << 32) | (unsigned)d;
    }
}

// ---------------- per-bucket CSR build ----------------

__global__ void bucket_csr_kernel(const unsigned long long* __restrict__ pairs,
                                  const int* __restrict__ bucketBase, int* __restrict__ counts,
                                  int* __restrict__ offs, float* __restrict__ dinv,
                                  int* __restrict__ ssrc, int N, int R) {
    __shared__ int h[256];
    __shared__ int loffs[256];
    __shared__ int cur[256];
    int b = blockIdx.x, tid = threadIdx.x;
    int nodeBase = b * R;
    int beg = bucketBase[b], end = bucketBase[b + 1];
    h[tid] = 0;
    __syncthreads();
    for (int i = beg + tid; i < end; i += 256) {
        int d = (int)(pairs[i] & 0xffffffffull);
        atomicAdd(&h[d - nodeBase], 1);
    }
    __syncthreads();
    int v = h[tid];
    loffs[tid] = v;
    __syncthreads();
    for (int off = 1; off < 256; off <<= 1) {
        int x = (tid >= off) ? loffs[tid - off] : 0;
        __syncthreads();
        loffs[tid] += x;
        __syncthreads();
    }
    int excl = loffs[tid] - v;
    cur[tid] = excl;
    int node = nodeBase + tid;
    if (tid < R && node < N) {
        counts[node] = v;
        offs[node] = beg + excl;
        dinv[node] = rsqrtf((float)v + 1.0f);  // +1 self-loop
    }
    __syncthreads();
    for (int i = beg + tid; i < end; i += 256) {
        unsigned long long p = pairs[i];
        int d = (int)(p & 0xffffffffull);
        int s = (int)(p >> 32);
        int r = atomicAdd(&cur[d - nodeBase], 1);
        ssrc[beg + r] = s;
    }
}

// ---------------- MFMA GEMM: X(M x 64) @ W(64 x OUTD) -> fp16, no LDS ----------------
// mfma_f32_16x16x32_f16, verified layouts:
//   A[m = lane&15][k = (lane>>4)*8 + j]      (8 f16 / lane)
//   B[k = (lane>>4)*8 + j][n = lane&15]
//   D col = lane&15, row = (lane>>4)*4 + reg

template <int OUTD, typename TIN>
__global__ void gemm_mfma_kernel(const TIN* __restrict__ X, const float* __restrict__ W,
                                 __half* __restrict__ H, int M, int ntiles) {
    constexpr int NC = OUTD / 16;
    const int lane = threadIdx.x & 63;
    const int wid  = threadIdx.x >> 6;
    const int q    = lane >> 4;
    const int m    = lane & 15;

    // B fragments (W is 64 x OUTD row-major), loaded once per block, reused across tiles
    half8 bfrag[2][NC];
#pragma unroll
    for (int s = 0; s < 2; ++s)
#pragma unroll
        for (int c = 0; c < NC; ++c)
#pragma unroll
            for (int j = 0; j < 8; ++j)
                bfrag[s][c][j] = (_Float16)W[(s * 32 + q * 8 + j) * OUTD + c * 16 + m];

    for (int tile = blockIdx.x * 4 + wid; tile < ntiles; tile += gridDim.x * 4) {
        int rowBase = tile * 16;
        int rowA = rowBase + m;
        if (rowA > M - 1) rowA = M - 1;

        half8 afrag[2];
        if constexpr (std::is_same<TIN, float>::value) {
            const float4* Xr = (const float4*)(X + (size_t)rowA * 64);
#pragma unroll
            for (int s = 0; s < 2; ++s) {
                float4 v0 = Xr[s * 8 + q * 2 + 0];
                float4 v1 = Xr[s * 8 + q * 2 + 1];
                afrag[s][0] = (_Float16)v0.x;
                afrag[s][1] = (_Float16)v0.y;
                afrag[s][2] = (_Float16)v0.z;
                afrag[s][3] = (_Float16)v0.w;
                afrag[s][4] = (_Float16)v1.x;
                afrag[s][5] = (_Float16)v1.y;
                afrag[s][6] = (_Float16)v1.z;
                afrag[s][7] = (_Float16)v1.w;
            }
        } else {
            const half8* Xr = (const half8*)(X + (size_t)rowA * 64);
#pragma unroll
            for (int s = 0; s < 2; ++s)
                afrag[s] = Xr[s * 4 + q];
        }

        floatx4 acc[NC];
#pragma unroll
        for (int c = 0; c < NC; ++c) acc[c] = (floatx4){0.f, 0.f, 0.f, 0.f};
#pragma unroll
        for (int s = 0; s < 2; ++s)
#pragma unroll
            for (int c = 0; c < NC; ++c)
                acc[c] = __builtin_amdgcn_mfma_f32_16x16x32_f16(afrag[s], bfrag[s][c], acc[c],
                                                                0, 0, 0);

#pragma unroll
        for (int r = 0; r < 4; ++r) {
            int row = rowBase + q * 4 + r;
            if (row < M) {
#pragma unroll
                for (int c = 0; c < NC; ++c)
                    H[(size_t)row * OUTD + c * 16 + m] = __float2half(acc[c][r]);
            }
        }
    }
}

// ---------------- CSR aggregation, D=64 fp16: wave/node, 4 edges per step ----------------

__global__ void agg64_kernel(const float2* __restrict__ hrow, const int* __restrict__ ssrc,
                             const int* __restrict__ offs, const int* __restrict__ counts,
                             const float* __restrict__ dinv, const float* __restrict__ bias,
                             float2* __restrict__ outrow, int N) {
    int wid  = threadIdx.x >> 6;
    int lane = threadIdx.x & 63;
    int node = blockIdx.x * 4 + wid;
    if (node >= N) return;
    int q = lane >> 4;
    int l = lane & 15;
    int beg = offs[node], cnt = counts[node];
    float a0 = 0.f, a1 = 0.f, a2 = 0.f, a3 = 0.f;
    for (int base = 0; base < cnt; base += 64) {
        int rem = cnt - base;
        if (rem > 64) rem = 64;
        int idx = 0;
        float dv = 0.0f;
        if (lane < rem) {
            idx = ssrc[beg + base + lane];
            dv  = dinv[idx];
        }
        for (int k = 0; k < rem; k += 4) {
            int e = k + q;
            int   s  = __shfl(idx, e, 64);
            float nv = __shfl(dv, e, 64);
            if (e < rem) {
                float2 raw = hrow[(size_t)s * 16 + l];
                float2 f0 = __half22float2(*(const __half2*)&raw.x);
                float2 f1 = __half22float2(*(const __half2*)&raw.y);
                a0 = fmaf(f0.x, nv, a0);
                a1 = fmaf(f0.y, nv, a1);
                a2 = fmaf(f1.x, nv, a2);
                a3 = fmaf(f1.y, nv, a3);
            }
        }
    }
    a0 += __shfl_xor(a0, 16, 64);
    a1 += __shfl_xor(a1, 16, 64);
    a2 += __shfl_xor(a2, 16, 64);
    a3 += __shfl_xor(a3, 16, 64);
    a0 += __shfl_xor(a0, 32, 64);
    a1 += __shfl_xor(a1, 32, 64);
    a2 += __shfl_xor(a2, 32, 64);
    a3 += __shfl_xor(a3, 32, 64);
    if (q == 0) {
        float dd = dinv[node];
        float2 raw = hrow[(size_t)node * 16 + l];
        float2 s0 = __half22float2(*(const __half2*)&raw.x);
        float2 s1 = __half22float2(*(const __half2*)&raw.y);
        float r0 = fmaxf(dd * (a0 + s0.x * dd) + bias[4 * l + 0], 0.0f);
        float r1 = fmaxf(dd * (a1 + s0.y * dd) + bias[4 * l + 1], 0.0f);
        float r2 = fmaxf(dd * (a2 + s1.x * dd) + bias[4 * l + 2], 0.0f);
        float r3 = fmaxf(dd * (a3 + s1.y * dd) + bias[4 * l + 3], 0.0f);
        __half2 p0 = __floats2half2_rn(r0, r1);
        __half2 p1 = __floats2half2_rn(r2, r3);
        float2 w;
        w.x = *(const float*)&p0;
        w.y = *(const float*)&p1;
        outrow[(size_t)node * 16 + l] = w;
    }
}

// ---------------- CSR aggregation, D=32 fp16: wave/node, 8 edges per step -> fp32 out ----------------

__global__ void agg32_kernel(const float2* __restrict__ hrow, const int* __restrict__ ssrc,
                             const int* __restrict__ offs, const int* __restrict__ counts,
                             const float* __restrict__ dinv, const float* __restrict__ bias,
                             float4* __restrict__ outrow, int N) {
    int wid  = threadIdx.x >> 6;
    int lane = threadIdx.x & 63;
    int node = blockIdx.x * 4 + wid;
    if (node >= N) return;
    int o = lane >> 3;
    int l = lane & 7;
    int beg = offs[node], cnt = counts[node];
    float a0 = 0.f, a1 = 0.f, a2 = 0.f, a3 = 0.f;
    for (int base = 0; base < cnt; base += 64) {
        int rem = cnt - base;
        if (rem > 64) rem = 64;
        int idx = 0;
        float dv = 0.0f;
        if (lane < rem) {
            idx = ssrc[beg + base + lane];
            dv  = dinv[idx];
        }
        for (int k = 0; k < rem; k += 8) {
            int e = k + o;
            int   s  = __shfl(idx, e, 64);
            float nv = __shfl(dv, e, 64);
            if (e < rem) {
                float2 raw = hrow[(size_t)s * 8 + l];
                float2 f0 = __half22float2(*(const __half2*)&raw.x);
                float2 f1 = __half22float2(*(const __half2*)&raw.y);
                a0 = fmaf(f0.x, nv, a0);
                a1 = fmaf(f0.y, nv, a1);
                a2 = fmaf(f1.x, nv, a2);
                a3 = fmaf(f1.y, nv, a3);
            }
        }
    }
    a0 += __shfl_xor(a0, 8, 64);
    a1 += __shfl_xor(a1, 8, 64);
    a2 += __shfl_xor(a2, 8, 64);
    a3 += __shfl_xor(a3, 8, 64);
    a0 += __shfl_xor(a0, 16, 64);
    a1 += __shfl_xor(a1, 16, 64);
    a2 += __shfl_xor(a2, 16, 64);
    a3 += __shfl_xor(a3, 16, 64);
    a0 += __shfl_xor(a0, 32, 64);
    a1 += __shfl_xor(a1, 32, 64);
    a2 += __shfl_xor(a2, 32, 64);
    a3 += __shfl_xor(a3, 32, 64);
    if (o == 0) {
        float dd = dinv[node];
        float2 raw = hrow[(size_t)node * 8 + l];
        float2 s0 = __half22float2(*(const __half2*)&raw.x);
        float2 s1 = __half22float2(*(const __half2*)&raw.y);
        float4 r;
        r.x = dd * (a0 + s0.x * dd) + bias[4 * l + 0];
        r.y = dd * (a1 + s0.y * dd) + bias[4 * l + 1];
        r.z = dd * (a2 + s1.x * dd) + bias[4 * l + 2];
        r.w = dd * (a3 + s1.y * dd) + bias[4 * l + 3];
        outrow[(size_t)node * 8 + l] = r;
    }
}

// ---------------- launch ----------------

extern "C" void kernel_launch(void* const* d_in, const int* in_sizes, int n_in,
                              void* d_out, int out_size, void* d_ws, size_t ws_size,
                              hipStream_t stream) {
    const float* x  = (const float*)d_in[0];
    const int*   ei = (const int*)d_in[1];
    const float* W1 = (const float*)d_in[2];
    const float* b1 = (const float*)d_in[3];
    const float* W2 = (const float*)d_in[4];
    const float* b2 = (const float*)d_in[5];
    float* out = (float*)d_out;

    const int N = in_sizes[0] / 64;   // 100000
    const int E = in_sizes[1] / 2;    // 1200000
    const int* src = ei;
    const int* dst = ei + E;

    const int Npad = (N + 1023) & ~1023;      // 100352
    const int R    = (N + NBUCK - 1) / NBUCK; // 196

    // workspace layout
    unsigned long long* pairs = (unsigned long long*)d_ws;    // E
    int*   ssrc   = (int*)(pairs + E);                        // E
    int*   counts = ssrc + E;                                 // Npad
    int*   offs   = counts + Npad;                            // Npad
    float* dinv   = (float*)(offs + Npad);                    // Npad
    int*   bucketCnt    = (int*)(dinv + Npad);                // NBUCK
    int*   bucketBase   = bucketCnt + NBUCK;                  // NBUCK+1
    int*   bucketCursor = bucketBase + NBUCK + 1;             // NBUCK (+1 pad)
    __half* h    = (__half*)(bucketCursor + NBUCK + 1);       // N*64 fp16
    __half* out1 = h + (size_t)N * 64;                        // N*64 fp16

    const int T = 256;

    // CSR build (bucketed, write-combining-friendly)
    hipMemsetAsync(bucketCnt, 0, NBUCK * sizeof(int), stream);
    bucket_hist_kernel<<<512, T, 0, stream>>>(dst, bucketCnt, E, R);
    bucket_scan_kernel<<<1, NBUCK, 0, stream>>>(bucketCnt, bucketBase, bucketCursor);
    partition_kernel<<<(E + 16383) / 16384, 1024, 0, stream>>>(src, dst, bucketCursor, pairs, E, R);
    bucket_csr_kernel<<<NBUCK, T, 0, stream>>>(pairs, bucketBase, counts, offs, dinv, ssrc, N, R);

    const int ntiles = (N + 15) / 16;  // 6250

    // layer 1
    gemm_mfma_kernel<64, float><<<782, T, 0, stream>>>(x, W1, h, N, ntiles);
    agg64_kernel<<<(N + 3) / 4, T, 0, stream>>>((const float2*)h, ssrc, offs, counts, dinv, b1,
                                                (float2*)out1, N);

    // layer 2 (h2 reuses h buffer)
    gemm_mfma_kernel<32, __half><<<782, T, 0, stream>>>(out1, W2, h, N, ntiles);
    agg32_kernel<<<(N + 3) / 4, T, 0, stream>>>((const float2*)h, ssrc, offs, counts, dinv, b2,
                                                (float4*)out, N);
}